// Round 12
// baseline (359.421 us; speedup 1.0000x reference)
//
#include <hip/hip_runtime.h>

// R12 = R11 with the x-staging bug fixed: with BB=32 the 448 staging slots
// span BOTH wave groups, so the per-step x prefetch/write is hoisted out of
// the grp branch (load before, LDS write after, pre-barrier). Structure:
// BB=32, grid 256 (1 block/CU), 8-wave layer-split, 2 N-tiles per wave
// (in-wave ILP twins), weights in regs, rational 7-trans packed-f32 act.

#define TT 256
#define II 14
#define BB 32
#define NTHREADS 512
#define XP 40  // xs row pitch (halfs)
#define HP 72  // hbuf row pitch (halfs)
#define HSTR 2304  // H buffer stride (halfs) = 32*72
#define XSTR 1280  // XS buffer stride (halfs) = 32*40
#define LOG2E 1.44269504088896340736f

typedef _Float16 f16x8 __attribute__((ext_vector_type(8)));
typedef _Float16 f16x4 __attribute__((ext_vector_type(4)));
typedef _Float16 f16x2 __attribute__((ext_vector_type(2)));
typedef float f32x4 __attribute__((ext_vector_type(4)));
typedef float f32x2 __attribute__((ext_vector_type(2)));

__device__ __forceinline__ f32x4 MFMA16(f16x8 a, f16x8 b, f32x4 c) {
  return __builtin_amdgcn_mfma_f32_16x16x32_f16(a, b, c, 0, 0, 0);
}

__device__ __forceinline__ float ex2(float x) {
#if __has_builtin(__builtin_amdgcn_exp2f)
  return __builtin_amdgcn_exp2f(x);
#else
  float r; asm("v_exp_f32 %0, %1" : "=v"(r) : "v"(x)); return r;
#endif
}
__device__ __forceinline__ float rcp_(float x) {
#if __has_builtin(__builtin_amdgcn_rcpf)
  return __builtin_amdgcn_rcpf(x);
#else
  float r; asm("v_rcp_f32 %0, %1" : "=v"(r) : "v"(x)); return r;
#endif
}
__device__ __forceinline__ f16x2 cvt_pk(float a, float b) {
#if __has_builtin(__builtin_amdgcn_cvt_pkrtz)
  return __builtin_bit_cast(f16x2, __builtin_amdgcn_cvt_pkrtz(a, b));
#else
  f16x2 r; r[0] = (_Float16)a; r[1] = (_Float16)b; return r;
#endif
}

// Pre-scaled gates (i,f,o: *-log2e ; g: *2log2e), u = 2^s (see R7 derivation).
__device__ __forceinline__ f16x4 lstm_act(f32x4 si, f32x4 sf, f32x4 sg, f32x4 so,
                                          f32x4& cs) {
  f16x4 hp;
#pragma unroll
  for (int p = 0; p < 2; ++p) {
    f32x2 ui, uf, ug, uo;
    ui.x = ex2(si[2 * p]); ui.y = ex2(si[2 * p + 1]);
    uf.x = ex2(sf[2 * p]); uf.y = ex2(sf[2 * p + 1]);
    ug.x = ex2(sg[2 * p]); ug.y = ex2(sg[2 * p + 1]);
    uo.x = ex2(so[2 * p]); uo.y = ex2(so[2 * p + 1]);
    const f32x2 one = {1.0f, 1.0f};
    const f32x2 fi = ui + one;
    const f32x2 ff = uf + one;
    const f32x2 fg = ug + one;
    const f32x2 pig = fi * fg;
    f32x2 cv; cv.x = cs[2 * p]; cv.y = cs[2 * p + 1];
    const f32x2 num = cv * pig + (ug - one) * ff;
    const f32x2 den = pig * ff;
    f32x2 rd; rd.x = rcp_(den.x); rd.y = rcp_(den.y);
    const f32x2 c = num * rd;
    cs[2 * p] = c.x; cs[2 * p + 1] = c.y;
    const f32x2 ctl = c * (f32x2){2.0f * LOG2E, 2.0f * LOG2E};
    f32x2 ut; ut.x = ex2(ctl.x); ut.y = ex2(ctl.y);
    const f32x2 dh = (uo + one) * (ut + one);
    f32x2 rh; rh.x = rcp_(dh.x); rh.y = rcp_(dh.y);
    const f32x2 h = (ut - one) * rh;
    const f16x2 h2 = cvt_pk(h.x, h.y);
    hp[2 * p] = h2[0];
    hp[2 * p + 1] = h2[1];
  }
  return hp;
}

__global__ void __launch_bounds__(NTHREADS, 2) fused_lstm(
    const float* __restrict__ x,
    const float* __restrict__ w_ih0, const float* __restrict__ w_hh0,
    const float* __restrict__ b_ih0, const float* __restrict__ b_hh0,
    const float* __restrict__ w_ih1, const float* __restrict__ w_hh1,
    const float* __restrict__ b_ih1, const float* __restrict__ b_hh1,
    const float* __restrict__ w_fc1, const float* __restrict__ b_fc1,
    const float* __restrict__ w_fc2, const float* __restrict__ b_fc2,
    float* __restrict__ out) {
  // LDS bytes: H1[2] @0 (2x4608) ; H0[2] @9216 (2x4608) ; XS[2] @18432 (2x2560)
  __shared__ char smem[23552];
  _Float16* H1 = (_Float16*)smem;
  _Float16* H0 = (_Float16*)(smem + 9216);
  _Float16* XS = (_Float16*)(smem + 18432);

  const int tid = threadIdx.x;
  const int wv = tid >> 6;
  const int grp = wv >> 2;   // 0: layer-0 waves, 1: layer-1 waves
  const int wl = wv & 3;     // hidden-tile index (16 units)
  const int l = tid & 63;
  const int row16 = l & 15;  // A: M row / B,C,D: N col (batch)
  const int kblk = l >> 4;   // A,B: k-block of 8 / C,D: row-block of 4

  const int b0 = blockIdx.x * BB;

  // ---- per-group weight A-fragments (one layer only), pre-scaled ----
  f16x8 wIn[4][2], wRec[4][2];
  f32x4 bias[4];
#pragma unroll
  for (int gt = 0; gt < 4; ++gt) {
    const float sc = (gt == 2) ? (2.0f * LOG2E) : (-LOG2E);
    const int g = gt * 64 + wl * 16 + row16;
    if (grp == 0) {
      f16x8 v;
#pragma unroll
      for (int j = 0; j < 8; ++j) {
        const int k = kblk * 8 + j;
        v[j] = (k < II) ? (_Float16)(w_ih0[g * II + k] * sc) : (_Float16)0.0f;
      }
      wIn[gt][0] = v;
#pragma unroll
      for (int ks = 0; ks < 2; ++ks) {
        const int ko = ks * 32 + kblk * 8;
        f16x8 vr;
#pragma unroll
        for (int j = 0; j < 8; ++j) vr[j] = (_Float16)(w_hh0[g * 64 + ko + j] * sc);
        wRec[gt][ks] = vr;
      }
    } else {
#pragma unroll
      for (int ks = 0; ks < 2; ++ks) {
        const int ko = ks * 32 + kblk * 8;
        f16x8 vi, vr;
#pragma unroll
        for (int j = 0; j < 8; ++j) vi[j] = (_Float16)(w_ih1[g * 64 + ko + j] * sc);
#pragma unroll
        for (int j = 0; j < 8; ++j) vr[j] = (_Float16)(w_hh1[g * 64 + ko + j] * sc);
        wIn[gt][ks] = vi;
        wRec[gt][ks] = vr;
      }
    }
    const int gb = gt * 64 + wl * 16 + kblk * 4;  // C/D row base
#pragma unroll
    for (int r = 0; r < 4; ++r) {
      bias[gt][r] = (grp == 0) ? (b_ih0[gb + r] + b_hh0[gb + r]) * sc
                               : (b_ih1[gb + r] + b_hh1[gb + r]) * sc;
    }
  }

  for (int i = tid; i < 23552 / 4; i += NTHREADS) ((int*)smem)[i] = 0;

  // x staging: BB*II = 448 slots; thread tid<448 owns one (row,k) — spans
  // BOTH groups, so staging is done OUTSIDE the grp branches below.
  const int n0 = tid / II, k0 = tid - n0 * II;
  const bool hasx = tid < BB * II;
  const float* xp0 = x + (size_t)(b0 + (hasx ? n0 : 0)) * (TT * II) + k0;

  __syncthreads();  // zeros done
  if (hasx) XS[n0 * XP + k0] = (_Float16)xp0[0];
  __syncthreads();  // x(0) staged

  f32x4 cs0 = {0.f, 0.f, 0.f, 0.f}, cs1 = {0.f, 0.f, 0.f, 0.f};

  // per-N-tile offsets (halfs)
  const int boffA = row16 * HP + kblk * 8;           // nt=0 B-frag
  const int boffB = (16 + row16) * HP + kblk * 8;    // nt=1 B-frag
  const int woffA = row16 * HP + wl * 16 + kblk * 4; // nt=0 publish
  const int woffB = (16 + row16) * HP + wl * 16 + kblk * 4;

  // ============ prologue t=0: grp0 computes h0(0); all stage x(1) ============
  {
    const float xn = hasx ? xp0[II] : 0.0f;  // x(1)
    if (grp == 0) {
      f32x4 accA[4], accB[4];
#pragma unroll
      for (int gt = 0; gt < 4; ++gt) { accA[gt] = bias[gt]; accB[gt] = bias[gt]; }
      const f16x8 bxA = *(const f16x8*)(XS + row16 * XP + kblk * 8);
      const f16x8 bxB = *(const f16x8*)(XS + (16 + row16) * XP + kblk * 8);
      // H0[1] is zeros; recurrent MFMAs on zero add nothing -> skip at t=0
      __builtin_amdgcn_s_setprio(1);
#pragma unroll
      for (int gt = 0; gt < 4; ++gt) {
        accA[gt] = MFMA16(wIn[gt][0], bxA, accA[gt]);
        accB[gt] = MFMA16(wIn[gt][0], bxB, accB[gt]);
      }
      __builtin_amdgcn_s_setprio(0);
      const f16x4 hA = lstm_act(accA[0], accA[1], accA[2], accA[3], cs0);
      const f16x4 hB = lstm_act(accB[0], accB[1], accB[2], accB[3], cs1);
      *(f16x4*)(H0 + woffA) = hA;
      *(f16x4*)(H0 + woffB) = hB;
    }
    if (hasx) XS[XSTR + n0 * XP + k0] = (_Float16)xn;
  }
  __syncthreads();

  // ============ main loop t=1..TT-1: grp0 L0(t), grp1 L1(t-1) ============
#pragma unroll 2
  for (int t = 1; t < TT; ++t) {
    const int pc = t & 1, pp = pc ^ 1;
    // x(t+1) prefetch: issued by ALL owner threads (both groups)
    const int tn = (t + 1 < TT) ? (t + 1) : (TT - 1);
    const float xn = hasx ? xp0[(size_t)tn * II] : 0.0f;

    if (grp == 0) {
      f32x4 accA[4], accB[4];
#pragma unroll
      for (int gt = 0; gt < 4; ++gt) { accA[gt] = bias[gt]; accB[gt] = bias[gt]; }
      const _Float16* xsb = XS + pc * XSTR;
      const _Float16* h0r = H0 + pp * HSTR;
      const f16x8 bxA = *(const f16x8*)(xsb + row16 * XP + kblk * 8);
      const f16x8 bxB = *(const f16x8*)(xsb + (16 + row16) * XP + kblk * 8);
      const f16x8 bhA0 = *(const f16x8*)(h0r + boffA);
      const f16x8 bhA1 = *(const f16x8*)(h0r + 32 + boffA);
      const f16x8 bhB0 = *(const f16x8*)(h0r + boffB);
      const f16x8 bhB1 = *(const f16x8*)(h0r + 32 + boffB);
      __builtin_amdgcn_s_setprio(1);
#pragma unroll
      for (int gt = 0; gt < 4; ++gt) {
        accA[gt] = MFMA16(wIn[gt][0], bxA, accA[gt]);
        accB[gt] = MFMA16(wIn[gt][0], bxB, accB[gt]);
        accA[gt] = MFMA16(wRec[gt][0], bhA0, accA[gt]);
        accB[gt] = MFMA16(wRec[gt][0], bhB0, accB[gt]);
        accA[gt] = MFMA16(wRec[gt][1], bhA1, accA[gt]);
        accB[gt] = MFMA16(wRec[gt][1], bhB1, accB[gt]);
      }
      __builtin_amdgcn_s_setprio(0);
      const f16x4 hA = lstm_act(accA[0], accA[1], accA[2], accA[3], cs0);
      const f16x4 hB = lstm_act(accB[0], accB[1], accB[2], accB[3], cs1);
      _Float16* h0w = H0 + pc * HSTR;
      *(f16x4*)(h0w + woffA) = hA;
      *(f16x4*)(h0w + woffB) = hB;
    } else {
      f32x4 accA[4], accB[4];
#pragma unroll
      for (int gt = 0; gt < 4; ++gt) { accA[gt] = bias[gt]; accB[gt] = bias[gt]; }
      const _Float16* h0r = H0 + pp * HSTR;  // h0(t-1)
      const _Float16* h1r = H1 + pc * HSTR;  // h1(t-2)
      const f16x8 bgA0 = *(const f16x8*)(h0r + boffA);
      const f16x8 bgA1 = *(const f16x8*)(h0r + 32 + boffA);
      const f16x8 bgB0 = *(const f16x8*)(h0r + boffB);
      const f16x8 bgB1 = *(const f16x8*)(h0r + 32 + boffB);
      const f16x8 bhA0 = *(const f16x8*)(h1r + boffA);
      const f16x8 bhA1 = *(const f16x8*)(h1r + 32 + boffA);
      const f16x8 bhB0 = *(const f16x8*)(h1r + boffB);
      const f16x8 bhB1 = *(const f16x8*)(h1r + 32 + boffB);
      __builtin_amdgcn_s_setprio(1);
#pragma unroll
      for (int gt = 0; gt < 4; ++gt) {
        accA[gt] = MFMA16(wIn[gt][0], bgA0, accA[gt]);
        accB[gt] = MFMA16(wIn[gt][0], bgB0, accB[gt]);
        accA[gt] = MFMA16(wIn[gt][1], bgA1, accA[gt]);
        accB[gt] = MFMA16(wIn[gt][1], bgB1, accB[gt]);
        accA[gt] = MFMA16(wRec[gt][0], bhA0, accA[gt]);
        accB[gt] = MFMA16(wRec[gt][0], bhB0, accB[gt]);
        accA[gt] = MFMA16(wRec[gt][1], bhA1, accA[gt]);
        accB[gt] = MFMA16(wRec[gt][1], bhB1, accB[gt]);
      }
      __builtin_amdgcn_s_setprio(0);
      const f16x4 hA = lstm_act(accA[0], accA[1], accA[2], accA[3], cs0);
      const f16x4 hB = lstm_act(accB[0], accB[1], accB[2], accB[3], cs1);
      _Float16* h1w = H1 + pp * HSTR;
      *(f16x4*)(h1w + woffA) = hA;
      *(f16x4*)(h1w + woffB) = hB;
    }
    // x(t+1) -> XS[pp] (WAR-safe: XS[pp] last read before previous barrier)
    if (hasx) XS[pp * XSTR + n0 * XP + k0] = (_Float16)xn;
    __syncthreads();
  }

  // ============ epilogue: grp1 computes h1(TT-1) ============
  if (grp == 1) {  // pc=0, pp=1
    f32x4 accA[4], accB[4];
#pragma unroll
    for (int gt = 0; gt < 4; ++gt) { accA[gt] = bias[gt]; accB[gt] = bias[gt]; }
    const _Float16* h0r = H0 + HSTR;  // h0(TT-1)
    const _Float16* h1r = H1;          // h1(TT-2)
    const f16x8 bgA0 = *(const f16x8*)(h0r + boffA);
    const f16x8 bgA1 = *(const f16x8*)(h0r + 32 + boffA);
    const f16x8 bgB0 = *(const f16x8*)(h0r + boffB);
    const f16x8 bgB1 = *(const f16x8*)(h0r + 32 + boffB);
    const f16x8 bhA0 = *(const f16x8*)(h1r + boffA);
    const f16x8 bhA1 = *(const f16x8*)(h1r + 32 + boffA);
    const f16x8 bhB0 = *(const f16x8*)(h1r + boffB);
    const f16x8 bhB1 = *(const f16x8*)(h1r + 32 + boffB);
    __builtin_amdgcn_s_setprio(1);
#pragma unroll
    for (int gt = 0; gt < 4; ++gt) {
      accA[gt] = MFMA16(wIn[gt][0], bgA0, accA[gt]);
      accB[gt] = MFMA16(wIn[gt][0], bgB0, accB[gt]);
      accA[gt] = MFMA16(wIn[gt][1], bgA1, accA[gt]);
      accB[gt] = MFMA16(wIn[gt][1], bgB1, accB[gt]);
      accA[gt] = MFMA16(wRec[gt][0], bhA0, accA[gt]);
      accB[gt] = MFMA16(wRec[gt][0], bhB0, accB[gt]);
      accA[gt] = MFMA16(wRec[gt][1], bhA1, accA[gt]);
      accB[gt] = MFMA16(wRec[gt][1], bhB1, accB[gt]);
    }
    __builtin_amdgcn_s_setprio(0);
    const f16x4 hA = lstm_act(accA[0], accA[1], accA[2], accA[3], cs0);
    const f16x4 hB = lstm_act(accB[0], accB[1], accB[2], accB[3], cs1);
    _Float16* h1w = H1 + HSTR;
    *(f16x4*)(h1w + woffA) = hA;
    *(f16x4*)(h1w + woffB) = hB;
  }
  __syncthreads();

  // ============ FC head (512 threads, 32 rows) ============
  const _Float16* h1f = H1 + HSTR;       // h1(TT-1)
  float* zbuf = (float*)(smem + 9216);   // overlays H0 (dead), 32*64*4 = 8192B
  {
    float4 w1r[16];
#pragma unroll
    for (int k4 = 0; k4 < 16; ++k4)
      w1r[k4] = *(const float4*)(w_fc1 + l * 64 + k4 * 4);
    const float b1l = b_fc1[l];
#pragma unroll
    for (int bi = 0; bi < 4; ++bi) {
      const int n = wv * 4 + bi;
      float s = b1l;
#pragma unroll
      for (int k4 = 0; k4 < 16; ++k4) {
        const float4 wq = w1r[k4];
        s = fmaf((float)h1f[n * HP + k4 * 4 + 0], wq.x, s);
        s = fmaf((float)h1f[n * HP + k4 * 4 + 1], wq.y, s);
        s = fmaf((float)h1f[n * HP + k4 * 4 + 2], wq.z, s);
        s = fmaf((float)h1f[n * HP + k4 * 4 + 3], wq.w, s);
      }
      zbuf[n * 64 + l] = fmaxf(s, 0.0f);
    }
  }
  __syncthreads();
  if (tid < 2 * BB) {
    const int n = tid >> 1, cc = tid & 1;
    float s = b_fc2[cc];
    for (int j = 0; j < 64; ++j) s = fmaf(w_fc2[cc * 64 + j], zbuf[n * 64 + j], s);
    out[(size_t)(b0 + n) * 2 + cc] = s;
  }
}

extern "C" void kernel_launch(void* const* d_in, const int* in_sizes, int n_in,
                              void* d_out, int out_size, void* d_ws, size_t ws_size,
                              hipStream_t stream) {
  (void)in_sizes; (void)n_in; (void)d_ws; (void)ws_size; (void)out_size;
  const float* x = (const float*)d_in[0];
  const float* w_ih0 = (const float*)d_in[1];
  const float* w_hh0 = (const float*)d_in[2];
  const float* b_ih0 = (const float*)d_in[3];
  const float* b_hh0 = (const float*)d_in[4];
  const float* w_ih1 = (const float*)d_in[5];
  const float* w_hh1 = (const float*)d_in[6];
  const float* b_ih1 = (const float*)d_in[7];
  const float* b_hh1 = (const float*)d_in[8];
  const float* w_fc1 = (const float*)d_in[9];
  const float* b_fc1 = (const float*)d_in[10];
  const float* w_fc2 = (const float*)d_in[11];
  const float* b_fc2 = (const float*)d_in[12];

  fused_lstm<<<dim3(8192 / BB), dim3(NTHREADS), 0, stream>>>(
      x, w_ih0, w_hh0, b_ih0, b_hh0, w_ih1, w_hh1, b_ih1, b_hh1,
      w_fc1, b_fc1, w_fc2, b_fc2, (float*)d_out);
}

// Round 13
// 324.472 us; speedup vs baseline: 1.1077x; 1.1077x over previous
//
#include <hip/hip_runtime.h>

// R13: cross-barrier software pipelining. Per step, only the 8 recurrent MFMAs
// sit between barrier and act; the input-projection MFMAs for the NEXT step
// (operands one barrier old) run in a tail phase after publish, overlapping
// other waves' trans-heavy act windows. grp0 = L0(t) (x triple-buffered, tail
// builds W_ih0*x(t+1)); grp1 = L1(t-2) (2-step skew, tail builds
// W_ih1*h0(t-1)). Bias rides as MFMA C operand. FP order identical to R10.

#define TT 256
#define II 14
#define BB 16
#define NTHREADS 512
#define XP 40        // xs row pitch (halfs)
#define HP 72        // h row pitch (halfs)
#define HSTR 1152    // halfs per H buffer (16*72)
#define XSTR 640     // halfs per XS buffer (16*40)
#define LOG2E 1.44269504088896340736f

typedef _Float16 f16x8 __attribute__((ext_vector_type(8)));
typedef _Float16 f16x4 __attribute__((ext_vector_type(4)));
typedef _Float16 f16x2 __attribute__((ext_vector_type(2)));
typedef float f32x4 __attribute__((ext_vector_type(4)));
typedef float f32x2 __attribute__((ext_vector_type(2)));

__device__ __forceinline__ f32x4 MFMA16(f16x8 a, f16x8 b, f32x4 c) {
  return __builtin_amdgcn_mfma_f32_16x16x32_f16(a, b, c, 0, 0, 0);
}

__device__ __forceinline__ float ex2(float x) {
#if __has_builtin(__builtin_amdgcn_exp2f)
  return __builtin_amdgcn_exp2f(x);
#else
  float r; asm("v_exp_f32 %0, %1" : "=v"(r) : "v"(x)); return r;
#endif
}
__device__ __forceinline__ float rcp_(float x) {
#if __has_builtin(__builtin_amdgcn_rcpf)
  return __builtin_amdgcn_rcpf(x);
#else
  float r; asm("v_rcp_f32 %0, %1" : "=v"(r) : "v"(x)); return r;
#endif
}
__device__ __forceinline__ f16x2 cvt_pk(float a, float b) {
#if __has_builtin(__builtin_amdgcn_cvt_pkrtz)
  return __builtin_bit_cast(f16x2, __builtin_amdgcn_cvt_pkrtz(a, b));
#else
  f16x2 r; r[0] = (_Float16)a; r[1] = (_Float16)b; return r;
#endif
}

// Pre-scaled gates (i,f,o: *-log2e ; g: *2log2e), u = 2^s (R7 derivation).
__device__ __forceinline__ f16x4 lstm_act(f32x4 si, f32x4 sf, f32x4 sg, f32x4 so,
                                          f32x4& cs) {
  f16x4 hp;
#pragma unroll
  for (int p = 0; p < 2; ++p) {
    f32x2 ui, uf, ug, uo;
    ui.x = ex2(si[2 * p]); ui.y = ex2(si[2 * p + 1]);
    uf.x = ex2(sf[2 * p]); uf.y = ex2(sf[2 * p + 1]);
    ug.x = ex2(sg[2 * p]); ug.y = ex2(sg[2 * p + 1]);
    uo.x = ex2(so[2 * p]); uo.y = ex2(so[2 * p + 1]);
    const f32x2 one = {1.0f, 1.0f};
    const f32x2 fi = ui + one;
    const f32x2 ff = uf + one;
    const f32x2 fg = ug + one;
    const f32x2 pig = fi * fg;
    f32x2 cv; cv.x = cs[2 * p]; cv.y = cs[2 * p + 1];
    const f32x2 num = cv * pig + (ug - one) * ff;
    const f32x2 den = pig * ff;
    f32x2 rd; rd.x = rcp_(den.x); rd.y = rcp_(den.y);
    const f32x2 c = num * rd;
    cs[2 * p] = c.x; cs[2 * p + 1] = c.y;
    const f32x2 ctl = c * (f32x2){2.0f * LOG2E, 2.0f * LOG2E};
    f32x2 ut; ut.x = ex2(ctl.x); ut.y = ex2(ctl.y);
    const f32x2 dh = (uo + one) * (ut + one);
    f32x2 rh; rh.x = rcp_(dh.x); rh.y = rcp_(dh.y);
    const f32x2 h = (ut - one) * rh;
    const f16x2 h2 = cvt_pk(h.x, h.y);
    hp[2 * p] = h2[0];
    hp[2 * p + 1] = h2[1];
  }
  return hp;
}

__global__ void __launch_bounds__(NTHREADS, 4) fused_lstm(
    const float* __restrict__ x,
    const float* __restrict__ w_ih0, const float* __restrict__ w_hh0,
    const float* __restrict__ b_ih0, const float* __restrict__ b_hh0,
    const float* __restrict__ w_ih1, const float* __restrict__ w_hh1,
    const float* __restrict__ b_ih1, const float* __restrict__ b_hh1,
    const float* __restrict__ w_fc1, const float* __restrict__ b_fc1,
    const float* __restrict__ w_fc2, const float* __restrict__ b_fc2,
    float* __restrict__ out) {
  // LDS bytes: H1[2] @0 (2x2304) ; H0[2] @4608 (2x2304) ; XS[3] @9216 (3x1280)
  __shared__ char smem[13056];
  _Float16* H1 = (_Float16*)smem;
  _Float16* H0 = (_Float16*)(smem + 4608);
  _Float16* XS = (_Float16*)(smem + 9216);

  const int tid = threadIdx.x;
  const int wv = tid >> 6;
  const int grp = wv >> 2;   // 0: layer-0 waves, 1: layer-1 waves
  const int wl = wv & 3;     // hidden-tile index (16 units)
  const int l = tid & 63;
  const int row16 = l & 15;  // A: M row / B,C,D: N col (batch)
  const int kblk = l >> 4;   // A,B: k-block of 8 / C,D: row-block of 4
  const int b0 = blockIdx.x * BB;

  // ---- per-group weight A-fragments, pre-scaled ----
  f16x8 wIn[4][2], wRec[4][2];
  f32x4 bias[4];
#pragma unroll
  for (int gt = 0; gt < 4; ++gt) {
    const float sc = (gt == 2) ? (2.0f * LOG2E) : (-LOG2E);
    const int g = gt * 64 + wl * 16 + row16;
    if (grp == 0) {
      f16x8 v;
#pragma unroll
      for (int j = 0; j < 8; ++j) {
        const int k = kblk * 8 + j;
        v[j] = (k < II) ? (_Float16)(w_ih0[g * II + k] * sc) : (_Float16)0.0f;
      }
      wIn[gt][0] = v;
      wIn[gt][1] = v;  // unused
#pragma unroll
      for (int ks = 0; ks < 2; ++ks) {
        const int ko = ks * 32 + kblk * 8;
        f16x8 vr;
#pragma unroll
        for (int j = 0; j < 8; ++j) vr[j] = (_Float16)(w_hh0[g * 64 + ko + j] * sc);
        wRec[gt][ks] = vr;
      }
    } else {
#pragma unroll
      for (int ks = 0; ks < 2; ++ks) {
        const int ko = ks * 32 + kblk * 8;
        f16x8 vi, vr;
#pragma unroll
        for (int j = 0; j < 8; ++j) vi[j] = (_Float16)(w_ih1[g * 64 + ko + j] * sc);
#pragma unroll
        for (int j = 0; j < 8; ++j) vr[j] = (_Float16)(w_hh1[g * 64 + ko + j] * sc);
        wIn[gt][ks] = vi;
        wRec[gt][ks] = vr;
      }
    }
    const int gb = gt * 64 + wl * 16 + kblk * 4;
#pragma unroll
    for (int r = 0; r < 4; ++r) {
      bias[gt][r] = (grp == 0) ? (b_ih0[gb + r] + b_hh0[gb + r]) * sc
                               : (b_ih1[gb + r] + b_hh1[gb + r]) * sc;
    }
  }

  for (int i = tid; i < 13056 / 4; i += NTHREADS) ((int*)smem)[i] = 0;

  // x staging: BB*II = 224 slots, all inside grp0's waves (tid < 224 < 256)
  const int n0 = tid / II, k0 = tid - n0 * II;
  const bool hasx = tid < BB * II;
  const float* xp0 = x + (size_t)(b0 + (hasx ? n0 : 0)) * (TT * II) + k0;

  __syncthreads();  // zeros done
  if (hasx) {
    XS[n0 * XP + k0] = (_Float16)xp0[0];                 // x(0) -> XS[0]
    XS[XSTR + n0 * XP + k0] = (_Float16)xp0[II];         // x(1) -> XS[1]
  }
  __syncthreads();

  f32x4 cs = {0.f, 0.f, 0.f, 0.f};
  const int boff = row16 * HP + kblk * 8;
  const int woff = row16 * HP + wl * 16 + kblk * 4;

  f32x4 accA[4], accB[4];

  // ================= prologue t=0 =================
  if (grp == 0) {
    const f16x8 bx0 = *(const f16x8*)(XS + row16 * XP + kblk * 8);
#pragma unroll
    for (int gt = 0; gt < 4; ++gt) accB[gt] = MFMA16(wIn[gt][0], bx0, bias[gt]);
    // recurrent operand h0(-1)=0: skip those MFMAs
    const f16x4 hp = lstm_act(accB[0], accB[1], accB[2], accB[3], cs);
    *(f16x4*)(H0 + woff) = hp;  // h0(0) -> H0[0] (parity 0)
    // tail: step-1 x-part
    const f16x8 bx1 = *(const f16x8*)(XS + XSTR + row16 * XP + kblk * 8);
#pragma unroll
    for (int gt = 0; gt < 4; ++gt) accA[gt] = MFMA16(wIn[gt][0], bx1, bias[gt]);
  } else {
#pragma unroll
    for (int gt = 0; gt < 4; ++gt) { accA[gt] = bias[gt]; accB[gt] = bias[gt]; }
  }
  if (hasx) XS[2 * XSTR + n0 * XP + k0] = (_Float16)xp0[2 * II];  // x(2) -> XS[2]
  __syncthreads();

  // ================= main loop t=1..TT-1 =================
  int hpub = HSTR, hrd = 0;                 // H parity: t odd -> publish HSTR
  int xsA = XSTR, xsB = 2 * XSTR, xsC = 0;  // x(t) / x(t+1) / stage x(t+2)

  auto step = [&](int t, f32x4(&accC)[4], f32x4(&accN)[4]) {
    // early global x prefetch (hidden under everything)
    const int tn = (t + 2 < TT) ? (t + 2) : (TT - 1);
    const float xn = hasx ? xp0[(size_t)tn * II] : 0.0f;
    if (grp == 0) {
      // phase 1: 8 recurrent MFMAs (only thing between barrier and act)
      const f16x8 bhA = *(const f16x8*)(H0 + hrd + boff);
      const f16x8 bhB = *(const f16x8*)(H0 + hrd + 32 + boff);
      __builtin_amdgcn_s_setprio(1);
#pragma unroll
      for (int gt = 0; gt < 4; ++gt) {
        accC[gt] = MFMA16(wRec[gt][0], bhA, accC[gt]);
        accC[gt] = MFMA16(wRec[gt][1], bhB, accC[gt]);
      }
      __builtin_amdgcn_s_setprio(0);
      // phase 2: act + publish h0(t)
      const f16x4 hp = lstm_act(accC[0], accC[1], accC[2], accC[3], cs);
      *(f16x4*)(H0 + hpub + woff) = hp;
      // phase 3 (tail): step t+1 x-part, overlaps other waves' act
      const f16x8 bx = *(const f16x8*)(XS + xsB + row16 * XP + kblk * 8);
#pragma unroll
      for (int gt = 0; gt < 4; ++gt) accN[gt] = MFMA16(wIn[gt][0], bx, bias[gt]);
    } else {
      // phase 1: 8 recurrent MFMAs for L1(t-2): h1(t-3) @ parity hrd
      const f16x8 bhA = *(const f16x8*)(H1 + hrd + boff);
      const f16x8 bhB = *(const f16x8*)(H1 + hrd + 32 + boff);
      __builtin_amdgcn_s_setprio(1);
#pragma unroll
      for (int gt = 0; gt < 4; ++gt) {
        accC[gt] = MFMA16(wRec[gt][0], bhA, accC[gt]);
        accC[gt] = MFMA16(wRec[gt][1], bhB, accC[gt]);
      }
      __builtin_amdgcn_s_setprio(0);
      // phase 2: act s=t-2 (valid from t>=2) + publish h1(t-2)
      if (t >= 2) {
        const f16x4 hp = lstm_act(accC[0], accC[1], accC[2], accC[3], cs);
        *(f16x4*)(H1 + hpub + woff) = hp;
      }
      // phase 3 (tail): step t-1 input-part W_ih1 * h0(t-1)
      const f16x8 bgA = *(const f16x8*)(H0 + hrd + boff);
      const f16x8 bgB = *(const f16x8*)(H0 + hrd + 32 + boff);
#pragma unroll
      for (int gt = 0; gt < 4; ++gt) {
        accN[gt] = MFMA16(wIn[gt][0], bgA, bias[gt]);
        accN[gt] = MFMA16(wIn[gt][1], bgB, accN[gt]);
      }
    }
    if (hasx) XS[xsC + n0 * XP + k0] = (_Float16)xn;  // x(t+2)
    __syncthreads();
    int tmp = hpub; hpub = hrd; hrd = tmp;
    int tA = xsA; xsA = xsB; xsB = xsC; xsC = tA;
  };

  for (int t = 1; t < TT - 1; t += 2) {  // t = 1..253 -> sub-steps 1..254
    step(t, accA, accB);
    step(t + 1, accB, accA);
  }
  step(TT - 1, accA, accB);  // t=255; leaves grp1's s=254 partial in accB

  // ================= epilogue: grp1 finishes s=254, 255 =================
  if (grp == 1) {
    // s=254: += W_hh1 * h1(253)  [published at t=255 -> H1+HSTR]
    const f16x8 bhA = *(const f16x8*)(H1 + HSTR + boff);
    const f16x8 bhB = *(const f16x8*)(H1 + HSTR + 32 + boff);
#pragma unroll
    for (int gt = 0; gt < 4; ++gt) {
      accB[gt] = MFMA16(wRec[gt][0], bhA, accB[gt]);
      accB[gt] = MFMA16(wRec[gt][1], bhB, accB[gt]);
    }
    const f16x4 hp = lstm_act(accB[0], accB[1], accB[2], accB[3], cs);
    *(f16x4*)(H1 + woff) = hp;  // h1(254) -> H1[0] (parity 0)
  }
  __syncthreads();
  if (grp == 1) {
    // s=255: bias + W_ih1*h0(255) + W_hh1*h1(254)
    const f16x8 bgA = *(const f16x8*)(H0 + HSTR + boff);  // h0(255), parity 1
    const f16x8 bgB = *(const f16x8*)(H0 + HSTR + 32 + boff);
    const f16x8 bhA = *(const f16x8*)(H1 + boff);          // h1(254)
    const f16x8 bhB = *(const f16x8*)(H1 + 32 + boff);
#pragma unroll
    for (int gt = 0; gt < 4; ++gt) {
      accA[gt] = MFMA16(wIn[gt][0], bgA, bias[gt]);
      accA[gt] = MFMA16(wIn[gt][1], bgB, accA[gt]);
      accA[gt] = MFMA16(wRec[gt][0], bhA, accA[gt]);
      accA[gt] = MFMA16(wRec[gt][1], bhB, accA[gt]);
    }
    const f16x4 hp = lstm_act(accA[0], accA[1], accA[2], accA[3], cs);
    *(f16x4*)(H1 + HSTR + woff) = hp;  // h1(255) -> H1[HSTR]
  }
  __syncthreads();

  // ================= FC head (512 threads) =================
  const _Float16* h1f = (const _Float16*)(smem + 2304);  // H1 + HSTR
  float* zbuf = (float*)(smem + 4608);                   // overlays H0 (dead)
  {
    float4 w1r[16];
#pragma unroll
    for (int k4 = 0; k4 < 16; ++k4)
      w1r[k4] = *(const float4*)(w_fc1 + l * 64 + k4 * 4);
    const float b1l = b_fc1[l];
#pragma unroll
    for (int bi = 0; bi < 2; ++bi) {
      const int n = wv * 2 + bi;
      float s = b1l;
#pragma unroll
      for (int k4 = 0; k4 < 16; ++k4) {
        const float4 wq = w1r[k4];
        s = fmaf((float)h1f[n * HP + k4 * 4 + 0], wq.x, s);
        s = fmaf((float)h1f[n * HP + k4 * 4 + 1], wq.y, s);
        s = fmaf((float)h1f[n * HP + k4 * 4 + 2], wq.z, s);
        s = fmaf((float)h1f[n * HP + k4 * 4 + 3], wq.w, s);
      }
      zbuf[n * 64 + l] = fmaxf(s, 0.0f);
    }
  }
  __syncthreads();
  if (tid < 2 * BB) {
    const int n = tid >> 1, cc = tid & 1;
    float s = b_fc2[cc];
    for (int j = 0; j < 64; ++j) s = fmaf(w_fc2[cc * 64 + j], zbuf[n * 64 + j], s);
    out[(size_t)(b0 + n) * 2 + cc] = s;
  }
}

extern "C" void kernel_launch(void* const* d_in, const int* in_sizes, int n_in,
                              void* d_out, int out_size, void* d_ws, size_t ws_size,
                              hipStream_t stream) {
  (void)in_sizes; (void)n_in; (void)d_ws; (void)ws_size; (void)out_size;
  const float* x = (const float*)d_in[0];
  const float* w_ih0 = (const float*)d_in[1];
  const float* w_hh0 = (const float*)d_in[2];
  const float* b_ih0 = (const float*)d_in[3];
  const float* b_hh0 = (const float*)d_in[4];
  const float* w_ih1 = (const float*)d_in[5];
  const float* w_hh1 = (const float*)d_in[6];
  const float* b_ih1 = (const float*)d_in[7];
  const float* b_hh1 = (const float*)d_in[8];
  const float* w_fc1 = (const float*)d_in[9];
  const float* b_fc1 = (const float*)d_in[10];
  const float* w_fc2 = (const float*)d_in[11];
  const float* b_fc2 = (const float*)d_in[12];

  fused_lstm<<<dim3(8192 / BB), dim3(NTHREADS), 0, stream>>>(
      x, w_ih0, w_hh0, b_ih0, b_hh0, w_ih1, w_hh1, b_ih1, b_hh1,
      w_fc1, b_fc1, w_fc2, b_fc2, (float*)d_out);
}